// Round 5
// baseline (319.445 us; speedup 1.0000x reference)
//
#include <hip/hip_runtime.h>
#include <math.h>

#define EPS 1e-7f

constexpr int SIZE_IN = 14;
constexpr int P_  = 36;   // 6x6 parent positions
constexpr int Cc  = 288;  // children per parent (3*3*32)
constexpr int O_  = 32;   // output capsules
constexpr int THREADS = 1024;
constexpr int CI = THREADS / O_;   // 32 child residue classes
constexpr int NT = Cc / CI;        // 9 children per thread
constexpr int NW = THREADS / 64;   // 16 waves per block
constexpr int NWR = 8;             // reduction buffers (two-stage: waves 8..15 fold into 0..7)

// LDS layout: ~57 KB (< 64 KB static limit); one 16-wave block per CU
struct __align__(16) SMem {
    float pose[Cc * 16];      // 18 KB  gathered child poses
    float act[Cc];            //  1.1 KB child activations
    float red[NWR][O_][33];   // 33.8 KB cross-wave reduction (stride 33: conflict-free)
    float mean[O_][17];       //  2.1 KB (stride 17: conflict-free)
    float iv[O_][17];         //  2.1 KB 1/(2*std^2+eps)
    float zb[O_];             // log(out_act+eps) + prob_main
};

#define F4_TO_ARR(dst, off, f4) \
    dst[(off)+0] = (f4).x; dst[(off)+1] = (f4).y; dst[(off)+2] = (f4).z; dst[(off)+3] = (f4).w;

// One EM pass. HASE: fused E-step (uses mean/iv/zb from previous M-step) feeding new M-step.
// LAST: write outputs instead of storing params for a next pass.
template<bool HASE, bool LAST>
__device__ __forceinline__ void em_pass(
    SMem& sm, const float* __restrict__ W,
    const float* __restrict__ beta_a, const float* __restrict__ beta_v,
    float lambda, int bp, float* __restrict__ out)
{
    const int tid = threadIdx.x;
    const int o  = tid & 31;   // output capsule owned by this lane
    const int ci = tid >> 5;   // child residue class (0..31)

    float m[16], iv[16], zb = 0.f;
    if (HASE) {
        #pragma unroll
        for (int j = 0; j < 16; ++j) { m[j] = sm.mean[o][j]; iv[j] = sm.iv[o][j]; }
        zb = sm.zb[o];
    }

    float S0 = 0.f, S1[16], S2[16];
    #pragma unroll
    for (int j = 0; j < 16; ++j) { S1[j] = 0.f; S2[j] = 0.f; }

    // prefetch t=0 (child c = ci)
    const float4* wp0 = reinterpret_cast<const float4*>(W + (size_t)(ci * O_ + o) * 16);
    float4 nw0 = wp0[0], nw1 = wp0[1], nw2 = wp0[2], nw3 = wp0[3];
    const float4* pp0 = reinterpret_cast<const float4*>(&sm.pose[ci * 16]);
    float4 np0 = pp0[0], np1 = pp0[1], np2 = pp0[2], np3 = pp0[3];

    #pragma unroll 2
    for (int t = 0; t < NT; ++t) {
        const int c = t * CI + ci;
        float w[16], q[16];
        F4_TO_ARR(w, 0, nw0) F4_TO_ARR(w, 4, nw1) F4_TO_ARR(w, 8, nw2) F4_TO_ARR(w, 12, nw3)
        F4_TO_ARR(q, 0, np0) F4_TO_ARR(q, 4, np1) F4_TO_ARR(q, 8, np2) F4_TO_ARR(q, 12, np3)
        if (t + 1 < NT) {  // prefetch next child
            const int cn = c + CI;
            const float4* wn = reinterpret_cast<const float4*>(W + (size_t)(cn * O_ + o) * 16);
            nw0 = wn[0]; nw1 = wn[1]; nw2 = wn[2]; nw3 = wn[3];
            const float4* pn = reinterpret_cast<const float4*>(&sm.pose[cn * 16]);
            np0 = pn[0]; np1 = pn[1]; np2 = pn[2]; np3 = pn[3];
        }

        // votes[i*4+jj] = sum_k q[i*4+k] * w[k*4+jj]   (4x4 matmul, 64 FMA)
        float v[16];
        #pragma unroll
        for (int i = 0; i < 4; ++i) {
            #pragma unroll
            for (int jj = 0; jj < 4; ++jj) {
                float acc = q[i*4+0] * w[0*4+jj];
                acc = fmaf(q[i*4+1], w[1*4+jj], acc);
                acc = fmaf(q[i*4+2], w[2*4+jj], acc);
                acc = fmaf(q[i*4+3], w[3*4+jj], acc);
                v[i*4+jj] = acc;
            }
        }

        float ws;
        if (HASE) {
            // E-step: zz = zb - sum_j (v-m)^2 * inv(2std^2+eps); softmax over o (32 lanes)
            float s = 0.f;
            #pragma unroll
            for (int j = 0; j < 16; ++j) { float d = v[j] - m[j]; s = fmaf(d * d, iv[j], s); }
            float zz = zb - s;
            float mx = zz;
            #pragma unroll
            for (int k = 16; k; k >>= 1) mx = fmaxf(mx, __shfl_xor(mx, k));
            float e = __expf(zz - mx);
            float sum = e;
            #pragma unroll
            for (int k = 16; k; k >>= 1) sum += __shfl_xor(sum, k);
            float rr = e / sum;
            ws = rr * sm.act[c];
        } else {
            ws = sm.act[c] * (1.0f / 32.0f);   // iteration 0: rr uniform
        }

        // M-step moment accumulation
        S0 += ws;
        #pragma unroll
        for (int j = 0; j < 16; ++j) {
            float t0 = ws * v[j];
            S1[j] += t0;
            S2[j] = fmaf(t0, v[j], S2[j]);
        }
    }

    // reduce over ci: pairwise within wave (lanes x and x^32 share o), then two-stage LDS fold
    S0 += __shfl_xor(S0, 32);
    #pragma unroll
    for (int j = 0; j < 16; ++j) {
        S1[j] += __shfl_xor(S1[j], 32);
        S2[j] += __shfl_xor(S2[j], 32);
    }
    const int wv = tid >> 6;  // 0..15
    if (!(tid & 32) && wv < NWR) {          // stage 1: waves 0..7 write
        float* r = sm.red[wv][o];
        r[0] = S0;
        #pragma unroll
        for (int j = 0; j < 16; ++j) { r[1 + j] = S1[j]; r[17 + j] = S2[j]; }
    }
    __syncthreads();
    if (!(tid & 32) && wv >= NWR) {         // stage 2: waves 8..15 fold in (one writer/slot)
        float* r = sm.red[wv - NWR][o];
        r[0] += S0;
        #pragma unroll
        for (int j = 0; j < 16; ++j) { r[1 + j] += S1[j]; r[17 + j] += S2[j]; }
    }
    __syncthreads();

    // finalize: one thread per (o, j) pair — threads 0..511
    if (tid < 512) {
        const int of = tid >> 4, jf = tid & 15;
        float s0 = 0.f, s1 = 0.f, s2 = 0.f;
        #pragma unroll
        for (int w = 0; w < NWR; ++w) {
            s0 += sm.red[w][of][0];        // broadcast within 16-lane group
            s1 += sm.red[w][of][1 + jf];
            s2 += sm.red[w][of][17 + jf];
        }
        float denom = s0 + EPS;
        float mj = s1 / denom;
        // sum rr*(v-m)^2 = S2 - 2 m S1 + m^2 S0 (clamped for fp safety)
        float varn = fmaxf(s2 - 2.f * mj * s1 + mj * mj * s0, 0.f);
        float sd = sqrtf(varn / denom);
        float lg = __logf(sd + EPS);
        float sumlog = lg;
        #pragma unroll
        for (int k = 1; k < 16; k <<= 1) sumlog += __shfl_xor(sumlog, k);  // reduce over j lanes
        if (!LAST) {
            sm.mean[of][jf] = mj;
            sm.iv[of][jf] = 1.f / fmaf(2.f * sd, sd, EPS);
            if (jf == 0) {
                float cost = fmaf(16.f, beta_v[of], s0 * sumlog);
                float oact = 1.f / (1.f + __expf(-(lambda * (beta_a[of] - cost))));
                sm.zb[of] = __logf(oact + EPS) - sumlog;   // log(act+eps) + prob_main
            }
        } else {
            out[8 * P_ * O_ + (size_t)(bp * O_ + of) * 16 + jf] = mj;
            if (jf == 0) {
                float cost = fmaf(16.f, beta_v[of], s0 * sumlog);
                float oact = 1.f / (1.f + __expf(-(lambda * (beta_a[of] - cost))));
                out[bp * O_ + of] = oact;
            }
        }
    }
    __syncthreads();
}

// NOTE: __launch_bounds__ 2nd arg measured (round 2) to act as min-BLOCKS-per-CU on this
// toolchain: (512,4) forced an 8-wave/EU 64-VGPR cap and catastrophic spill. (1024,1)
// -> 16 waves/CU -> 4 waves/EU -> 128-VGPR cap, which fits the ~100-reg working set.
__global__ __launch_bounds__(THREADS, 1) void convcaps_kernel(
    const float* __restrict__ in_act, const float* __restrict__ in_pose,
    const float* __restrict__ W, const float* __restrict__ beta_a,
    const float* __restrict__ beta_v, float* __restrict__ out)
{
    __shared__ SMem sm;
    const int bp = blockIdx.x;
    const int b  = bp / P_;
    const int p  = bp % P_;
    const int tid = threadIdx.x;
    const int row0 = (p / 6) * 2, col0 = (p % 6) * 2;

    // gather 9 child pixels: pose (9 x 512 contiguous floats) and act (9 x 32)
    for (int f = tid; f < 9 * 128; f += THREADS) {
        const int qw = f >> 7, r = f & 127;
        const int pix = (row0 + qw / 3) * SIZE_IN + (col0 + qw % 3);
        reinterpret_cast<float4*>(sm.pose)[qw * 128 + r] =
            reinterpret_cast<const float4*>(in_pose + (size_t)(b * 196 + pix) * 512)[r];
    }
    for (int idx = tid; idx < Cc; idx += THREADS) {
        const int qw = idx >> 5, ic = idx & 31;
        const int pix = (row0 + qw / 3) * SIZE_IN + (col0 + qw % 3);
        sm.act[idx] = in_act[(size_t)(b * 196 + pix) * 32 + ic];
    }
    __syncthreads();

    // 3 routing iterations -> 3 fused passes over children
    em_pass<false, false>(sm, W, beta_a, beta_v, 0.0f,      bp, out);  // M1 (lambda=0 -> act=0.5)
    em_pass<true,  false>(sm, W, beta_a, beta_v, 0.0005f,   bp, out);  // E1+M2
    em_pass<true,  true >(sm, W, beta_a, beta_v, 0.000975f, bp, out);  // E2+M3 -> outputs
}

extern "C" void kernel_launch(void* const* d_in, const int* in_sizes, int n_in,
                              void* d_out, int out_size, void* d_ws, size_t ws_size,
                              hipStream_t stream) {
    const float* in_act  = (const float*)d_in[0];
    const float* in_pose = (const float*)d_in[1];
    const float* W       = (const float*)d_in[2];
    const float* beta_a  = (const float*)d_in[3];
    const float* beta_v  = (const float*)d_in[4];
    float* out = (float*)d_out;

    convcaps_kernel<<<dim3(8 * P_), dim3(THREADS), 0, stream>>>(
        in_act, in_pose, W, beta_a, beta_v, out);
}

// Round 8
// 143.800 us; speedup vs baseline: 2.2215x; 2.2215x over previous
//
#include <hip/hip_runtime.h>
#include <math.h>

#define EPS 1e-7f

constexpr int SIZE_IN = 14;
constexpr int P_  = 36;   // 6x6 parent positions
constexpr int Cc  = 288;  // children per parent (3*3*32)
constexpr int O_  = 32;   // output capsules
constexpr int THREADS = 256;

// LDS layout: 40 KB total
struct __align__(16) SMem {
    float pose[Cc * 16];      // 18 KB  gathered child poses
    float act[Cc];            //  1.1 KB child activations
    float red[4][O_][33];     // 16.9 KB cross-wave reduction scratch (stride 33: conflict-free)
    float mean[O_][17];       //  2.2 KB padded (stride 17: conflict-free)
    float iv[O_][17];         //  2.2 KB 1/(2*std^2+eps)
    float zb[O_];             // log(out_act+eps) + prob_main
};

#define F4_TO_ARR(dst, off, f4) \
    dst[(off)+0] = (f4).x; dst[(off)+1] = (f4).y; dst[(off)+2] = (f4).z; dst[(off)+3] = (f4).w;

// ---- DPP-based 32-lane butterfly reductions (rocPRIM-style) ----
// __shfl_xor lowers to LDS-pipe ops (~30-60cy each); DPP row ops are ~4cy VALU.
// Reduction-only pairings (valid because sub-groups are value-uniform before each step):
//   step1 xor1 : quad_perm(1,0,3,2) = 0xB1 -> pairs equal
//   step2 xor2 : quad_perm(2,3,0,1) = 0x4E -> quads equal
//   step3      : row_half_mirror    = 0x141 -> lane i<-7-i in 8-group: other quad -> octets equal
//   step4      : row_mirror         = 0x140 -> lane i<-15-i in 16-group: other octet -> rows equal
//   step5 xor16: ds_swizzle 0x401F  -> crosses 16s within each 32-lane half
template<int CTRL>
__device__ __forceinline__ float dppf(float x) {
    int xi = __builtin_bit_cast(int, x);
    return __builtin_bit_cast(float,
        __builtin_amdgcn_update_dpp(xi, xi, CTRL, 0xf, 0xf, true));
}
__device__ __forceinline__ float swz16(float x) {
    return __builtin_bit_cast(float,
        __builtin_amdgcn_ds_swizzle(__builtin_bit_cast(int, x), 0x401F));
}
__device__ __forceinline__ float red32_max(float x) {
    x = fmaxf(x, dppf<0xB1>(x));
    x = fmaxf(x, dppf<0x4E>(x));
    x = fmaxf(x, dppf<0x141>(x));
    x = fmaxf(x, dppf<0x140>(x));
    x = fmaxf(x, swz16(x));
    return x;
}
__device__ __forceinline__ float red32_sum(float x) {
    x += dppf<0xB1>(x);
    x += dppf<0x4E>(x);
    x += dppf<0x141>(x);
    x += dppf<0x140>(x);
    x += swz16(x);
    return x;
}
__device__ __forceinline__ float red16_sum(float x) {  // 16-lane groups (finalize sumlog)
    x += dppf<0xB1>(x);
    x += dppf<0x4E>(x);
    x += dppf<0x141>(x);
    x += dppf<0x140>(x);
    return x;
}

// One EM pass. HASE: fused E-step (uses mean/iv/zb from previous M-step) feeding new M-step.
// LAST: write outputs instead of storing params for a next pass.
template<bool HASE, bool LAST>
__device__ __forceinline__ void em_pass(
    SMem& sm, const float* __restrict__ W,
    const float* __restrict__ beta_a, const float* __restrict__ beta_v,
    float lambda, int bp, float* __restrict__ out)
{
    const int tid = threadIdx.x;
    const int o  = tid & 31;   // output capsule owned by this lane
    const int ci = tid >> 5;   // child residue class (0..7)

    float m[16], iv[16], zb = 0.f;
    if (HASE) {
        #pragma unroll
        for (int j = 0; j < 16; ++j) { m[j] = sm.mean[o][j]; iv[j] = sm.iv[o][j]; }
        zb = sm.zb[o];
    }

    float S0 = 0.f, S1[16], S2[16];
    #pragma unroll
    for (int j = 0; j < 16; ++j) { S1[j] = 0.f; S2[j] = 0.f; }

    // prefetch t=0 (child c = ci)
    const float4* wp0 = reinterpret_cast<const float4*>(W + (size_t)(ci * O_ + o) * 16);
    float4 nw0 = wp0[0], nw1 = wp0[1], nw2 = wp0[2], nw3 = wp0[3];
    const float4* pp0 = reinterpret_cast<const float4*>(&sm.pose[ci * 16]);
    float4 np0 = pp0[0], np1 = pp0[1], np2 = pp0[2], np3 = pp0[3];

    #pragma unroll 2
    for (int t = 0; t < 36; ++t) {
        const int c = t * 8 + ci;
        float w[16], q[16];
        F4_TO_ARR(w, 0, nw0) F4_TO_ARR(w, 4, nw1) F4_TO_ARR(w, 8, nw2) F4_TO_ARR(w, 12, nw3)
        F4_TO_ARR(q, 0, np0) F4_TO_ARR(q, 4, np1) F4_TO_ARR(q, 8, np2) F4_TO_ARR(q, 12, np3)
        if (t + 1 < 36) {  // prefetch next child
            const int cn = c + 8;
            const float4* wn = reinterpret_cast<const float4*>(W + (size_t)(cn * O_ + o) * 16);
            nw0 = wn[0]; nw1 = wn[1]; nw2 = wn[2]; nw3 = wn[3];
            const float4* pn = reinterpret_cast<const float4*>(&sm.pose[cn * 16]);
            np0 = pn[0]; np1 = pn[1]; np2 = pn[2]; np3 = pn[3];
        }

        // votes[i*4+jj] = sum_k q[i*4+k] * w[k*4+jj]   (4x4 matmul, 64 FMA)
        float v[16];
        #pragma unroll
        for (int i = 0; i < 4; ++i) {
            #pragma unroll
            for (int jj = 0; jj < 4; ++jj) {
                float acc = q[i*4+0] * w[0*4+jj];
                acc = fmaf(q[i*4+1], w[1*4+jj], acc);
                acc = fmaf(q[i*4+2], w[2*4+jj], acc);
                acc = fmaf(q[i*4+3], w[3*4+jj], acc);
                v[i*4+jj] = acc;
            }
        }

        float ws;
        if (HASE) {
            // E-step: zz = zb - sum_j (v-m)^2 * inv(2std^2+eps); softmax over o (32 lanes)
            float s = 0.f;
            #pragma unroll
            for (int j = 0; j < 16; ++j) { float d = v[j] - m[j]; s = fmaf(d * d, iv[j], s); }
            float zz = zb - s;
            float mx = red32_max(zz);
            float e = __expf(zz - mx);
            float sum = red32_sum(e);
            float rr = e / sum;
            ws = rr * sm.act[c];
        } else {
            ws = sm.act[c] * (1.0f / 32.0f);   // iteration 0: rr uniform
        }

        // M-step moment accumulation
        S0 += ws;
        #pragma unroll
        for (int j = 0; j < 16; ++j) {
            float t0 = ws * v[j];
            S1[j] += t0;
            S2[j] = fmaf(t0, v[j], S2[j]);
        }
    }

    // reduce over ci: pairwise within wave (lanes x and x^32 share o), then LDS across 4 waves
    S0 += __shfl_xor(S0, 32);
    #pragma unroll
    for (int j = 0; j < 16; ++j) {
        S1[j] += __shfl_xor(S1[j], 32);
        S2[j] += __shfl_xor(S2[j], 32);
    }
    if (!(tid & 32)) {
        const int wv = tid >> 6;
        float* r = sm.red[wv][o];
        r[0] = S0;
        #pragma unroll
        for (int j = 0; j < 16; ++j) { r[1 + j] = S1[j]; r[17 + j] = S2[j]; }
    }
    __syncthreads();

    // finalize: one thread per (o, j) pair — 256 threads = 16 o-groups of 16 j-lanes;
    // handle o in two halves
    #pragma unroll
    for (int half = 0; half < 2; ++half) {
        const int of = (tid >> 4) + half * 16, jf = tid & 15;
        const float* r0 = sm.red[0][of];
        const float* r1 = sm.red[1][of];
        const float* r2 = sm.red[2][of];
        const float* r3 = sm.red[3][of];
        float s0 = r0[0] + r1[0] + r2[0] + r3[0];
        float s1 = r0[1+jf] + r1[1+jf] + r2[1+jf] + r3[1+jf];
        float s2 = r0[17+jf] + r1[17+jf] + r2[17+jf] + r3[17+jf];
        float denom = s0 + EPS;
        float mj = s1 / denom;
        // sum rr*(v-m)^2 = S2 - 2 m S1 + m^2 S0 (clamped for fp safety)
        float varn = fmaxf(s2 - 2.f * mj * s1 + mj * mj * s0, 0.f);
        float sd = sqrtf(varn / denom);
        float sumlog = red16_sum(__logf(sd + EPS));   // reduce over the 16 j-lanes
        if (!LAST) {
            sm.mean[of][jf] = mj;
            sm.iv[of][jf] = 1.f / fmaf(2.f * sd, sd, EPS);
            if (jf == 0) {
                float cost = fmaf(16.f, beta_v[of], s0 * sumlog);
                float oact = 1.f / (1.f + __expf(-(lambda * (beta_a[of] - cost))));
                sm.zb[of] = __logf(oact + EPS) - sumlog;   // log(act+eps) + prob_main
            }
        } else {
            out[8 * P_ * O_ + (size_t)(bp * O_ + of) * 16 + jf] = mj;
            if (jf == 0) {
                float cost = fmaf(16.f, beta_v[of], s0 * sumlog);
                float oact = 1.f / (1.f + __expf(-(lambda * (beta_a[of] - cost))));
                out[bp * O_ + of] = oact;
            }
        }
    }
    __syncthreads();
}

// NOTE (measured): workgroups >256 threads compiled to a hard 64-VGPR cap on this toolchain
// regardless of __launch_bounds__ 2nd arg — (512,4) and (1024,1) both spilled catastrophically
// (rounds 2/5: WRITE_SIZE 162->363 MB scratch traffic). (256,2) gives 100 VGPR, no spill.
__global__ __launch_bounds__(THREADS, 2) void convcaps_kernel(
    const float* __restrict__ in_act, const float* __restrict__ in_pose,
    const float* __restrict__ W, const float* __restrict__ beta_a,
    const float* __restrict__ beta_v, float* __restrict__ out)
{
    __shared__ SMem sm;
    const int bp = blockIdx.x;
    const int b  = bp / P_;
    const int p  = bp % P_;
    const int tid = threadIdx.x;
    const int row0 = (p / 6) * 2, col0 = (p % 6) * 2;

    // gather 9 child pixels: pose (9 x 512 contiguous floats) and act (9 x 32)
    for (int f = tid; f < 9 * 128; f += THREADS) {
        const int qw = f >> 7, r = f & 127;
        const int pix = (row0 + qw / 3) * SIZE_IN + (col0 + qw % 3);
        reinterpret_cast<float4*>(sm.pose)[qw * 128 + r] =
            reinterpret_cast<const float4*>(in_pose + (size_t)(b * 196 + pix) * 512)[r];
    }
    for (int idx = tid; idx < Cc; idx += THREADS) {
        const int qw = idx >> 5, ic = idx & 31;
        const int pix = (row0 + qw / 3) * SIZE_IN + (col0 + qw % 3);
        sm.act[idx] = in_act[(size_t)(b * 196 + pix) * 32 + ic];
    }
    __syncthreads();

    // 3 routing iterations -> 3 fused passes over children
    em_pass<false, false>(sm, W, beta_a, beta_v, 0.0f,      bp, out);  // M1 (lambda=0 -> act=0.5)
    em_pass<true,  false>(sm, W, beta_a, beta_v, 0.0005f,   bp, out);  // E1+M2
    em_pass<true,  true >(sm, W, beta_a, beta_v, 0.000975f, bp, out);  // E2+M3 -> outputs
}

extern "C" void kernel_launch(void* const* d_in, const int* in_sizes, int n_in,
                              void* d_out, int out_size, void* d_ws, size_t ws_size,
                              hipStream_t stream) {
    const float* in_act  = (const float*)d_in[0];
    const float* in_pose = (const float*)d_in[1];
    const float* W       = (const float*)d_in[2];
    const float* beta_a  = (const float*)d_in[3];
    const float* beta_v  = (const float*)d_in[4];
    float* out = (float*)d_out;

    convcaps_kernel<<<dim3(8 * P_), dim3(THREADS), 0, stream>>>(
        in_act, in_pose, W, beta_a, beta_v, out);
}